// Round 2
// baseline (4034.409 us; speedup 1.0000x reference)
//
#include <hip/hip_runtime.h>
#include <hip/hip_bf16.h>
#include <math.h>

#define TT 256
#define BB 64
#define HH 1024
#define VV 512
#define NEGV -10000.0f
#define BOSI 1

// ws layout:
//   [0, 1MiB)        : ET float32 [VV][VV]   (ET[j][i] = exp(trans[i][j]))
//   [1MiB, 17MiB)    : feats bf16 [BB][TT][VV]

// ---------------- ET[j][i] = exp(trans[i][j]) ----------------
__global__ __launch_bounds__(256)
void k_exp_T(const float* __restrict__ trans, float* __restrict__ ET) {
    int idx = blockIdx.x * 256 + threadIdx.x;   // 262144 total
    int i = idx >> 9;
    int j = idx & (VV - 1);
    ET[j * VV + i] = expf(trans[idx]);
}

// ---------------- feats GEMM: [T*B, H] x [V, H]^T + bias -> bf16 [B][T][V] ----
#define BM 64
#define BN 64
#define BK 32

__global__ __launch_bounds__(256)
void k_feats(const float* __restrict__ A, const float* __restrict__ W,
             const float* __restrict__ bias, __hip_bfloat16* __restrict__ feats) {
    // k-major LDS tiles (pad +4 keeps float4 reads 16B-aligned, breaks bank stride)
    __shared__ float As[BK][BM + 4];
    __shared__ float Bs[BK][BN + 4];
    int tid = threadIdx.x;
    int tx = tid & 15, ty = tid >> 4;
    int row0 = blockIdx.x * BM;
    int col0 = blockIdx.y * BN;
    float acc[4][4] = {};
    for (int kt = 0; kt < HH; kt += BK) {
#pragma unroll
        for (int s = 0; s < 2; ++s) {
            int slot = tid + s * 256;       // 0..511
            int row = slot >> 3;            // 0..63
            int f4 = slot & 7;              // 0..7  (float4 slot along K)
            float4 av = *(const float4*)&A[(size_t)(row0 + row) * HH + kt + f4 * 4];
            As[f4 * 4 + 0][row] = av.x; As[f4 * 4 + 1][row] = av.y;
            As[f4 * 4 + 2][row] = av.z; As[f4 * 4 + 3][row] = av.w;
            float4 bv = *(const float4*)&W[(size_t)(col0 + row) * HH + kt + f4 * 4];
            Bs[f4 * 4 + 0][row] = bv.x; Bs[f4 * 4 + 1][row] = bv.y;
            Bs[f4 * 4 + 2][row] = bv.z; Bs[f4 * 4 + 3][row] = bv.w;
        }
        __syncthreads();
#pragma unroll
        for (int k = 0; k < BK; ++k) {
            float4 a4 = *(const float4*)&As[k][ty * 4];
            float4 w4 = *(const float4*)&Bs[k][tx * 4];
            float av[4] = {a4.x, a4.y, a4.z, a4.w};
            float wv[4] = {w4.x, w4.y, w4.z, w4.w};
#pragma unroll
            for (int r = 0; r < 4; ++r)
#pragma unroll
                for (int c = 0; c < 4; ++c)
                    acc[r][c] = fmaf(av[r], wv[c], acc[r][c]);
        }
        __syncthreads();
    }
    float4 b4 = *(const float4*)&bias[col0 + tx * 4];
    float bv[4] = {b4.x, b4.y, b4.z, b4.w};
#pragma unroll
    for (int r = 0; r < 4; ++r) {
        int row = row0 + ty * 4 + r;   // row = t*BB + b
        int t = row >> 6;
        int bb = row & (BB - 1);
        __hip_bfloat16* dst = feats + ((size_t)bb * TT + t) * VV + col0 + tx * 4;
        __hip_bfloat162 p0, p1;
        p0.x = __float2bfloat16(acc[r][0] + bv[0]);
        p0.y = __float2bfloat16(acc[r][1] + bv[1]);
        p1.x = __float2bfloat16(acc[r][2] + bv[2]);
        p1.y = __float2bfloat16(acc[r][3] + bv[3]);
        *(__hip_bfloat162*)dst = p0;
        *(__hip_bfloat162*)(dst + 2) = p1;
    }
}

// ---------------- per-b log-semiring scan ----------------
// block b: score[i] in regs (2 per thread), p[j]=exp(score-m) in LDS,
// z[i] = m + log(sum_j ET[j][i]*p[j]) + feat[t][i]
__global__ __launch_bounds__(256)
void k_scan(const float* __restrict__ ET, const __hip_bfloat16* __restrict__ feats,
            const int* __restrict__ lengths, float* __restrict__ out) {
    int b = blockIdx.x;
    int tid = threadIdx.x;
    int lane = tid & 63, wid = tid >> 6;
    __shared__ float p[VV];
    __shared__ float red[4];
    __shared__ float red2[4];
    int len = lengths[b];
    float s0 = (2 * tid == BOSI) ? 0.f : NEGV;
    float s1 = (2 * tid + 1 == BOSI) ? 0.f : NEGV;
    const float2* ET2 = (const float2*)ET;
    const __hip_bfloat162* f2 = (const __hip_bfloat162*)(feats + (size_t)b * TT * VV);
    for (int t = 0; t < len; ++t) {
        // block max of score
        float lm = fmaxf(s0, s1);
#pragma unroll
        for (int off = 32; off > 0; off >>= 1)
            lm = fmaxf(lm, __shfl_xor(lm, off, 64));
        if (lane == 0) red[wid] = lm;
        __syncthreads();
        float m = fmaxf(fmaxf(red[0], red[1]), fmaxf(red[2], red[3]));
        *(float2*)&p[2 * tid] = make_float2(expf(s0 - m), expf(s1 - m));
        __syncthreads();
        // matvec: lane-coalesced float2 rows of ET, broadcast p[j]
        float a0 = 0.f, a1 = 0.f;
#pragma unroll 8
        for (int j = 0; j < VV; ++j) {
            float2 e = ET2[j * 256 + tid];
            float pj = p[j];
            a0 = fmaf(e.x, pj, a0);
            a1 = fmaf(e.y, pj, a1);
        }
        __hip_bfloat162 fv = f2[t * 256 + tid];
        s0 = m + logf(a0) + __bfloat162float(fv.x);
        s1 = m + logf(a1) + __bfloat162float(fv.y);
        __syncthreads();   // protect p/red before next step overwrites
    }
    // final LSE over i
    float lm = fmaxf(s0, s1);
#pragma unroll
    for (int off = 32; off > 0; off >>= 1)
        lm = fmaxf(lm, __shfl_xor(lm, off, 64));
    if (lane == 0) red[wid] = lm;
    __syncthreads();
    float m = fmaxf(fmaxf(red[0], red[1]), fmaxf(red[2], red[3]));
    float s = expf(s0 - m) + expf(s1 - m);
#pragma unroll
    for (int off = 32; off > 0; off >>= 1)
        s += __shfl_xor(s, off, 64);
    if (lane == 0) red2[wid] = s;
    __syncthreads();
    if (tid == 0) out[b] = m + logf(red2[0] + red2[1] + red2[2] + red2[3]);
}

extern "C" void kernel_launch(void* const* d_in, const int* in_sizes, int n_in,
                              void* d_out, int out_size, void* d_ws, size_t ws_size,
                              hipStream_t stream) {
    const float* enc     = (const float*)d_in[0];  // [T,B,H]
    const int*   lengths = (const int*)d_in[1];    // [B]
    const float* W       = (const float*)d_in[2];  // [V,H]
    const float* bias    = (const float*)d_in[3];  // [V]
    const float* trans   = (const float*)d_in[4];  // [V,V]
    float* out = (float*)d_out;

    float* ET = (float*)d_ws;
    __hip_bfloat16* feats = (__hip_bfloat16*)((char*)d_ws + (1 << 20));

    hipLaunchKernelGGL(k_exp_T, dim3(VV * VV / 256), dim3(256), 0, stream, trans, ET);
    hipLaunchKernelGGL(k_feats, dim3((TT * BB) / BM, VV / BN), dim3(256), 0, stream,
                       enc, W, bias, feats);
    hipLaunchKernelGGL(k_scan, dim3(BB), dim3(256), 0, stream, ET, feats, lengths, out);
}

// Round 3
// 2321.573 us; speedup vs baseline: 1.7378x; 1.7378x over previous
//
#include <hip/hip_runtime.h>
#include <hip/hip_bf16.h>
#include <math.h>

#define TT 256
#define BB 64
#define HH 1024
#define VV 512
#define NEGV -10000.0f
#define BOSI 1

// ws layout:
//   [0, 512KiB)      : ETb bf16 [VV][VV]   (ETb[j][i] = bf16(exp(trans[i][j])))
//   [1MiB, 17MiB)    : feats bf16 [BB][TT][VV]

// ---------------- ETb[j][i] = bf16(exp(trans[i][j])), LDS-tiled transpose ----
__global__ __launch_bounds__(256)
void k_expT_bf16(const float* __restrict__ trans, __hip_bfloat16* __restrict__ ETb) {
    __shared__ float tile[32][33];
    int bi = blockIdx.x;          // i-tile
    int bj = blockIdx.y;          // j-tile
    int tx = threadIdx.x & 31;
    int ty = threadIdx.x >> 5;    // 0..7
#pragma unroll
    for (int k = 0; k < 4; ++k) {
        int i = bi * 32 + ty + k * 8;
        tile[ty + k * 8][tx] = expf(trans[i * VV + bj * 32 + tx]);  // coalesced read
    }
    __syncthreads();
#pragma unroll
    for (int k = 0; k < 4; ++k) {
        int j = bj * 32 + ty + k * 8;
        ETb[j * VV + bi * 32 + tx] = __float2bfloat16(tile[tx][ty + k * 8]);  // coalesced write
    }
}

// ---------------- feats GEMM: [T*B, H] x [V, H]^T + bias -> bf16 [B][T][V] ----
#define BM 64
#define BN 64
#define BK 32

__global__ __launch_bounds__(256)
void k_feats(const float* __restrict__ A, const float* __restrict__ W,
             const float* __restrict__ bias, __hip_bfloat16* __restrict__ feats) {
    __shared__ float As[BK][BM + 4];
    __shared__ float Bs[BK][BN + 4];
    int tid = threadIdx.x;
    int tx = tid & 15, ty = tid >> 4;
    int row0 = blockIdx.x * BM;
    int col0 = blockIdx.y * BN;
    float acc[4][4] = {};
    for (int kt = 0; kt < HH; kt += BK) {
#pragma unroll
        for (int s = 0; s < 2; ++s) {
            int slot = tid + s * 256;
            int row = slot >> 3;
            int f4 = slot & 7;
            float4 av = *(const float4*)&A[(size_t)(row0 + row) * HH + kt + f4 * 4];
            As[f4 * 4 + 0][row] = av.x; As[f4 * 4 + 1][row] = av.y;
            As[f4 * 4 + 2][row] = av.z; As[f4 * 4 + 3][row] = av.w;
            float4 bv = *(const float4*)&W[(size_t)(col0 + row) * HH + kt + f4 * 4];
            Bs[f4 * 4 + 0][row] = bv.x; Bs[f4 * 4 + 1][row] = bv.y;
            Bs[f4 * 4 + 2][row] = bv.z; Bs[f4 * 4 + 3][row] = bv.w;
        }
        __syncthreads();
#pragma unroll
        for (int k = 0; k < BK; ++k) {
            float4 a4 = *(const float4*)&As[k][ty * 4];
            float4 w4 = *(const float4*)&Bs[k][tx * 4];
            float av[4] = {a4.x, a4.y, a4.z, a4.w};
            float wv[4] = {w4.x, w4.y, w4.z, w4.w};
#pragma unroll
            for (int r = 0; r < 4; ++r)
#pragma unroll
                for (int c = 0; c < 4; ++c)
                    acc[r][c] = fmaf(av[r], wv[c], acc[r][c]);
        }
        __syncthreads();
    }
    float4 b4 = *(const float4*)&bias[col0 + tx * 4];
    float bv[4] = {b4.x, b4.y, b4.z, b4.w};
#pragma unroll
    for (int r = 0; r < 4; ++r) {
        int row = row0 + ty * 4 + r;   // row = t*BB + b
        int t = row >> 6;
        int bb = row & (BB - 1);
        __hip_bfloat16* dst = feats + ((size_t)bb * TT + t) * VV + col0 + tx * 4;
        __hip_bfloat162 p0, p1;
        p0.x = __float2bfloat16(acc[r][0] + bv[0]);
        p0.y = __float2bfloat16(acc[r][1] + bv[1]);
        p1.x = __float2bfloat16(acc[r][2] + bv[2]);
        p1.y = __float2bfloat16(acc[r][3] + bv[3]);
        *(__hip_bfloat162*)dst = p0;
        *(__hip_bfloat162*)(dst + 2) = p1;
    }
}

// ---------------- per-b log-semiring scan ----------------
__device__ __forceinline__ float bflo(unsigned int u) { return __uint_as_float(u << 16); }
__device__ __forceinline__ float bfhi(unsigned int u) { return __uint_as_float(u & 0xffff0000u); }

__global__ __launch_bounds__(256)
void k_scan(const __hip_bfloat16* __restrict__ ETb, const __hip_bfloat16* __restrict__ feats,
            const int* __restrict__ lengths, float* __restrict__ out) {
    int b = blockIdx.x;
    int tid = threadIdx.x;
    int lane = tid & 63, wid = tid >> 6;
    __shared__ float p[VV];
    __shared__ float red[4];
    __shared__ float red2[4];
    int len = lengths[b];
    float s0 = (2 * tid == BOSI) ? 0.f : NEGV;
    float s1 = (2 * tid + 1 == BOSI) ? 0.f : NEGV;
    const unsigned int* ET2 = (const unsigned int*)ETb;   // [j][i-pair], 2 bf16 per uint
    const __hip_bfloat162* f2 = (const __hip_bfloat162*)(feats + (size_t)b * TT * VV);
    for (int t = 0; t < len; ++t) {
        // block max of score
        float lm = fmaxf(s0, s1);
#pragma unroll
        for (int off = 32; off > 0; off >>= 1)
            lm = fmaxf(lm, __shfl_xor(lm, off, 64));
        if (lane == 0) red[wid] = lm;
        __syncthreads();
        float m = fmaxf(fmaxf(red[0], red[1]), fmaxf(red[2], red[3]));
        *(float2*)&p[2 * tid] = make_float2(expf(s0 - m), expf(s1 - m));
        __syncthreads();
        // matvec: 32 outstanding 4B loads, 8 independent FMA chains
        float a00 = 0.f, a01 = 0.f, a10 = 0.f, a11 = 0.f;
        float a20 = 0.f, a21 = 0.f, a30 = 0.f, a31 = 0.f;
#pragma unroll 8
        for (int j = 0; j < VV; j += 4) {
            unsigned int e0 = ET2[(j + 0) * 256 + tid];
            unsigned int e1 = ET2[(j + 1) * 256 + tid];
            unsigned int e2 = ET2[(j + 2) * 256 + tid];
            unsigned int e3 = ET2[(j + 3) * 256 + tid];
            float4 pv = *(const float4*)&p[j];            // ds_read_b128, broadcast
            a00 = fmaf(bflo(e0), pv.x, a00); a01 = fmaf(bfhi(e0), pv.x, a01);
            a10 = fmaf(bflo(e1), pv.y, a10); a11 = fmaf(bfhi(e1), pv.y, a11);
            a20 = fmaf(bflo(e2), pv.z, a20); a21 = fmaf(bfhi(e2), pv.z, a21);
            a30 = fmaf(bflo(e3), pv.w, a30); a31 = fmaf(bfhi(e3), pv.w, a31);
        }
        float a0 = (a00 + a10) + (a20 + a30);
        float a1 = (a01 + a11) + (a21 + a31);
        __hip_bfloat162 fv = f2[t * 256 + tid];
        s0 = m + logf(a0) + __bfloat162float(fv.x);
        s1 = m + logf(a1) + __bfloat162float(fv.y);
        __syncthreads();   // protect p/red before next step overwrites
    }
    // final LSE over i
    float lm = fmaxf(s0, s1);
#pragma unroll
    for (int off = 32; off > 0; off >>= 1)
        lm = fmaxf(lm, __shfl_xor(lm, off, 64));
    if (lane == 0) red[wid] = lm;
    __syncthreads();
    float m = fmaxf(fmaxf(red[0], red[1]), fmaxf(red[2], red[3]));
    float s = expf(s0 - m) + expf(s1 - m);
#pragma unroll
    for (int off = 32; off > 0; off >>= 1)
        s += __shfl_xor(s, off, 64);
    if (lane == 0) red2[wid] = s;
    __syncthreads();
    if (tid == 0) out[b] = m + logf(red2[0] + red2[1] + red2[2] + red2[3]);
}

extern "C" void kernel_launch(void* const* d_in, const int* in_sizes, int n_in,
                              void* d_out, int out_size, void* d_ws, size_t ws_size,
                              hipStream_t stream) {
    const float* enc     = (const float*)d_in[0];  // [T,B,H]
    const int*   lengths = (const int*)d_in[1];    // [B]
    const float* W       = (const float*)d_in[2];  // [V,H]
    const float* bias    = (const float*)d_in[3];  // [V]
    const float* trans   = (const float*)d_in[4];  // [V,V]
    float* out = (float*)d_out;

    __hip_bfloat16* ETb   = (__hip_bfloat16*)d_ws;
    __hip_bfloat16* feats = (__hip_bfloat16*)((char*)d_ws + (1 << 20));

    hipLaunchKernelGGL(k_expT_bf16, dim3(16, 16), dim3(256), 0, stream, trans, ETb);
    hipLaunchKernelGGL(k_feats, dim3((TT * BB) / BM, VV / BN), dim3(256), 0, stream,
                       enc, W, bias, feats);
    hipLaunchKernelGGL(k_scan, dim3(BB), dim3(256), 0, stream, ETb, feats, lengths, out);
}

// Round 4
// 1594.033 us; speedup vs baseline: 2.5309x; 1.4564x over previous
//
#include <hip/hip_runtime.h>
#include <hip/hip_bf16.h>
#include <math.h>

#define TT 256
#define BB 64
#define HH 1024
#define VV 512
#define NEGV -10000.0f
#define BOSI 1
#define CI 128          // i-chunk per block
#define NK 4            // chunks (blocks) per batch element

// ws layout:
//   [0, 512K)            : ETb bf16 [VV][VV]  (ETb[j][i] = bf16(exp(trans[i][j])))
//   [1M, 17M)            : feats bf16 [BB][TT][VV]
//   [17M, 17M+256K)      : z double buffer: float [2][BB][VV]
//   [17M+256K, +8K)      : cnt: uint [BB][32]  (128B-padded per b)

// ---------------- ETb[j][i] = bf16(exp(trans[i][j])), LDS-tiled transpose ----
__global__ __launch_bounds__(256)
void k_expT_bf16(const float* __restrict__ trans, __hip_bfloat16* __restrict__ ETb) {
    __shared__ float tile[32][33];
    int bi = blockIdx.x, bj = blockIdx.y;
    int tx = threadIdx.x & 31;
    int ty = threadIdx.x >> 5;
#pragma unroll
    for (int k = 0; k < 4; ++k) {
        int i = bi * 32 + ty + k * 8;
        tile[ty + k * 8][tx] = expf(trans[i * VV + bj * 32 + tx]);
    }
    __syncthreads();
#pragma unroll
    for (int k = 0; k < 4; ++k) {
        int j = bj * 32 + ty + k * 8;
        ETb[j * VV + bi * 32 + tx] = __float2bfloat16(tile[tx][ty + k * 8]);
    }
}

// ---------------- zero the barrier counters ----------------
__global__ __launch_bounds__(256)
void k_zero(unsigned int* __restrict__ cnt) {
    cnt[blockIdx.x * 256 + threadIdx.x] = 0u;
}

// ---------------- feats GEMM: [T*B, H] x [V, H]^T + bias -> bf16 [B][T][V] ----
#define BM 64
#define BN 64
#define BK 32

__global__ __launch_bounds__(256)
void k_feats(const float* __restrict__ A, const float* __restrict__ W,
             const float* __restrict__ bias, __hip_bfloat16* __restrict__ feats) {
    __shared__ float As[BK][BM + 4];
    __shared__ float Bs[BK][BN + 4];
    int tid = threadIdx.x;
    int tx = tid & 15, ty = tid >> 4;
    int row0 = blockIdx.x * BM;
    int col0 = blockIdx.y * BN;
    float acc[4][4] = {};
    for (int kt = 0; kt < HH; kt += BK) {
#pragma unroll
        for (int s = 0; s < 2; ++s) {
            int slot = tid + s * 256;
            int row = slot >> 3;
            int f4 = slot & 7;
            float4 av = *(const float4*)&A[(size_t)(row0 + row) * HH + kt + f4 * 4];
            As[f4 * 4 + 0][row] = av.x; As[f4 * 4 + 1][row] = av.y;
            As[f4 * 4 + 2][row] = av.z; As[f4 * 4 + 3][row] = av.w;
            float4 bv = *(const float4*)&W[(size_t)(col0 + row) * HH + kt + f4 * 4];
            Bs[f4 * 4 + 0][row] = bv.x; Bs[f4 * 4 + 1][row] = bv.y;
            Bs[f4 * 4 + 2][row] = bv.z; Bs[f4 * 4 + 3][row] = bv.w;
        }
        __syncthreads();
#pragma unroll
        for (int k = 0; k < BK; ++k) {
            float4 a4 = *(const float4*)&As[k][ty * 4];
            float4 w4 = *(const float4*)&Bs[k][tx * 4];
            float av[4] = {a4.x, a4.y, a4.z, a4.w};
            float wv[4] = {w4.x, w4.y, w4.z, w4.w};
#pragma unroll
            for (int r = 0; r < 4; ++r)
#pragma unroll
                for (int c = 0; c < 4; ++c)
                    acc[r][c] = fmaf(av[r], wv[c], acc[r][c]);
        }
        __syncthreads();
    }
    float4 b4 = *(const float4*)&bias[col0 + tx * 4];
    float bv[4] = {b4.x, b4.y, b4.z, b4.w};
#pragma unroll
    for (int r = 0; r < 4; ++r) {
        int row = row0 + ty * 4 + r;   // row = t*BB + b
        int t = row >> 6;
        int bb = row & (BB - 1);
        __hip_bfloat16* dst = feats + ((size_t)bb * TT + t) * VV + col0 + tx * 4;
        __hip_bfloat162 p0, p1;
        p0.x = __float2bfloat16(acc[r][0] + bv[0]);
        p0.y = __float2bfloat16(acc[r][1] + bv[1]);
        p1.x = __float2bfloat16(acc[r][2] + bv[2]);
        p1.y = __float2bfloat16(acc[r][3] + bv[3]);
        *(__hip_bfloat162*)dst = p0;
        *(__hip_bfloat162*)(dst + 2) = p1;
    }
}

// ---------------- i-split scan: 4 blocks per b, LDS-resident ET slice --------
__device__ __forceinline__ float bflo(unsigned int u) { return __uint_as_float(u << 16); }
__device__ __forceinline__ float bfhi(unsigned int u) { return __uint_as_float(u & 0xffff0000u); }

// dynamic LDS layout (bytes):
//   [0, 131072)          sET  ushort [512][128]
//   [131072, 139392)     sp   float [4][520]   (replicas, 8-bank shift)
//   [139392, 147584)     spart float [16][128]
//   [147584, 147616)     sred float [8]
#define SMEM_BYTES 147616

__global__ __launch_bounds__(256, 1)
void k_scan(const unsigned short* __restrict__ ETb,
            const __hip_bfloat16* __restrict__ feats,
            const int* __restrict__ lengths,
            float* __restrict__ zbuf, unsigned int* __restrict__ cnt,
            float* __restrict__ out) {
    extern __shared__ unsigned char smem[];
    unsigned short* sET = (unsigned short*)smem;
    float* sp    = (float*)(smem + 131072);
    float* spart = (float*)(smem + 139392);
    float* sred  = (float*)(smem + 147584);

    int tid = threadIdx.x;
    int b   = blockIdx.x & 63;        // peers {b, b+64, b+128, b+192} -> same XCD (%8)
    int kc  = blockIdx.x >> 6;        // i-chunk 0..3
    int lane = tid & 63, wid = tid >> 6;
    int len = lengths[b];
    unsigned int* mycnt = cnt + b * 32;

    // ---- preload ET slice: columns [kc*128, kc*128+128) of all 512 rows ----
    {
        const uint4* Eg = (const uint4*)ETb;    // row = 64 uint4
        uint4* El = (uint4*)sET;                // row = 16 uint4
#pragma unroll
        for (int it = 0; it < 32; ++it) {
            int idx = tid + it * 256;           // 0..8191
            int j = idx >> 4, q = idx & 15;
            El[idx] = Eg[j * 64 + kc * 16 + q];
        }
    }

    float* z0 = zbuf;
    float* z1 = zbuf + BB * VV;

    // ---- init z buf0 slice (acts as "round 0" production) ----
    if (tid < CI) {
        int ig = kc * CI + tid;
        __hip_atomic_store(&z0[b * VV + ig], (ig == BOSI) ? 0.f : NEGV,
                           __ATOMIC_RELAXED, __HIP_MEMORY_SCOPE_AGENT);
    }

    unsigned roundv = 1;
    auto gbar = [&]() {
        __syncthreads();   // drains all waves' mem ops (compiler emits vmcnt(0) before s_barrier)
        if (tid == 0) {
            __hip_atomic_fetch_add(mycnt, 1u, __ATOMIC_ACQ_REL, __HIP_MEMORY_SCOPE_AGENT);
            unsigned tgt = NK * roundv;
            while (__hip_atomic_load(mycnt, __ATOMIC_ACQUIRE, __HIP_MEMORY_SCOPE_AGENT) < tgt)
                __builtin_amdgcn_s_sleep(1);
        }
        roundv++;
        __syncthreads();
    };
    gbar();   // all peers' init visible

    int js  = tid >> 4;               // j-slice 0..15 (32 j each)
    int il8 = (tid & 15) * 8;         // 8 i's per thread
    int rep = js & 3;                 // p replica (bank-shifted)
    const __hip_bfloat16* fb = feats + (size_t)b * TT * VV;

    for (int t = 0; t < len; ++t) {
        const float* zr = (t & 1) ? z1 : z0;
        float*       zw = (t & 1) ? z0 : z1;
        // read full score vector (coherent), compute m
        unsigned long long vz = __hip_atomic_load(
            (const unsigned long long*)(zr + b * VV) + tid,
            __ATOMIC_RELAXED, __HIP_MEMORY_SCOPE_AGENT);
        float s0f = __uint_as_float((unsigned int)vz);
        float s1f = __uint_as_float((unsigned int)(vz >> 32));
        float lm = fmaxf(s0f, s1f);
#pragma unroll
        for (int off = 32; off > 0; off >>= 1)
            lm = fmaxf(lm, __shfl_xor(lm, off, 64));
        if (lane == 0) sred[wid] = lm;
        __syncthreads();
        float m = fmaxf(fmaxf(sred[0], sred[1]), fmaxf(sred[2], sred[3]));
        float p0 = expf(s0f - m), p1 = expf(s1f - m);
#pragma unroll
        for (int r = 0; r < 4; ++r)
            *(float2*)&sp[r * 520 + 2 * tid] = make_float2(p0, p1);
        __syncthreads();

        // matvec over LDS ET slice: a[i] = sum_j ET[j][i] * p[j]
        float a0 = 0.f, a1 = 0.f, a2 = 0.f, a3 = 0.f;
        float a4 = 0.f, a5 = 0.f, a6 = 0.f, a7 = 0.f;
#pragma unroll
        for (int j4 = 0; j4 < 8; ++j4) {
            int j = js * 32 + j4 * 4;
            float4 pv = *(const float4*)&sp[rep * 520 + j];
            float pj[4] = {pv.x, pv.y, pv.z, pv.w};
#pragma unroll
            for (int jj = 0; jj < 4; ++jj) {
                uint4 e = *(const uint4*)&sET[(j + jj) * CI + il8];
                float pq = pj[jj];
                a0 = fmaf(bflo(e.x), pq, a0); a1 = fmaf(bfhi(e.x), pq, a1);
                a2 = fmaf(bflo(e.y), pq, a2); a3 = fmaf(bfhi(e.y), pq, a3);
                a4 = fmaf(bflo(e.z), pq, a4); a5 = fmaf(bfhi(e.z), pq, a5);
                a6 = fmaf(bflo(e.w), pq, a6); a7 = fmaf(bfhi(e.w), pq, a7);
            }
        }
        *(float4*)&spart[js * CI + il8]     = make_float4(a0, a1, a2, a3);
        *(float4*)&spart[js * CI + il8 + 4] = make_float4(a4, a5, a6, a7);
        __syncthreads();

        // reduce 16 j-slice partials, finish z_new slice, publish
        if (tid < CI) {
            float s = 0.f;
#pragma unroll
            for (int q = 0; q < 16; ++q) s += spart[q * CI + tid];
            int ig = kc * CI + tid;
            float ft = __bfloat162float(fb[(size_t)t * VV + ig]);
            float zn = m + logf(s) + ft;      // logf(0) = -inf for dead states: OK
            __hip_atomic_store(&zw[b * VV + ig], zn,
                               __ATOMIC_RELAXED, __HIP_MEMORY_SCOPE_AGENT);
        }
        gbar();
    }

    // ---- final LSE over all 512 states (chunk-0 block only) ----
    if (kc == 0) {
        const float* zf = (len & 1) ? z1 : z0;
        unsigned long long vz = __hip_atomic_load(
            (const unsigned long long*)(zf + b * VV) + tid,
            __ATOMIC_RELAXED, __HIP_MEMORY_SCOPE_AGENT);
        float s0f = __uint_as_float((unsigned int)vz);
        float s1f = __uint_as_float((unsigned int)(vz >> 32));
        float lm = fmaxf(s0f, s1f);
#pragma unroll
        for (int off = 32; off > 0; off >>= 1)
            lm = fmaxf(lm, __shfl_xor(lm, off, 64));
        if (lane == 0) sred[wid] = lm;
        __syncthreads();
        float m = fmaxf(fmaxf(sred[0], sred[1]), fmaxf(sred[2], sred[3]));
        float s = expf(s0f - m) + expf(s1f - m);
#pragma unroll
        for (int off = 32; off > 0; off >>= 1)
            s += __shfl_xor(s, off, 64);
        if (lane == 0) sred[4 + wid] = s;
        __syncthreads();
        if (tid == 0)
            out[b] = m + logf(sred[4] + sred[5] + sred[6] + sred[7]);
    }
}

extern "C" void kernel_launch(void* const* d_in, const int* in_sizes, int n_in,
                              void* d_out, int out_size, void* d_ws, size_t ws_size,
                              hipStream_t stream) {
    const float* enc     = (const float*)d_in[0];  // [T,B,H]
    const int*   lengths = (const int*)d_in[1];    // [B]
    const float* W       = (const float*)d_in[2];  // [V,H]
    const float* bias    = (const float*)d_in[3];  // [V]
    const float* trans   = (const float*)d_in[4];  // [V,V]
    float* out = (float*)d_out;

    char* ws = (char*)d_ws;
    __hip_bfloat16* ETb   = (__hip_bfloat16*)ws;
    __hip_bfloat16* feats = (__hip_bfloat16*)(ws + (1 << 20));
    float*          zbuf  = (float*)(ws + (17 << 20));
    unsigned int*   cnt   = (unsigned int*)(ws + (17 << 20) + (256 << 10));

    static bool attr_set = false;
    if (!attr_set) {
        hipFuncSetAttribute((const void*)k_scan,
                            hipFuncAttributeMaxDynamicSharedMemorySize, SMEM_BYTES);
        attr_set = true;
    }

    hipLaunchKernelGGL(k_zero, dim3(8), dim3(256), 0, stream, cnt);
    hipLaunchKernelGGL(k_expT_bf16, dim3(16, 16), dim3(256), 0, stream, trans, ETb);
    hipLaunchKernelGGL(k_feats, dim3((TT * BB) / BM, VV / BN), dim3(256), 0, stream,
                       enc, W, bias, feats);
    hipLaunchKernelGGL(k_scan, dim3(NK * BB), dim3(256), SMEM_BYTES, stream,
                       (const unsigned short*)ETb, feats, lengths, zbuf, cnt, out);
}

// Round 5
// 1381.780 us; speedup vs baseline: 2.9197x; 1.1536x over previous
//
#include <hip/hip_runtime.h>
#include <hip/hip_bf16.h>
#include <math.h>

#define TT 256
#define BB 64
#define HH 1024
#define VV 512
#define NEGV -10000.0f
#define BOSI 1
#define CI 128          // i-chunk per block
#define NK 4            // chunks (blocks) per batch element

// ws layout:
//   [0, 512K)            : ETb bf16 [VV][VV]  (ETb[j][i] = bf16(exp(trans[i][j])))
//   [1M, 17M)            : feats bf16 [BB][TT][VV]
//   [17M, 17M+256K)      : z double buffer: float [2][BB][VV]
//   [17M+256K, +8K)      : flags: ull [BB][16]  (128B-padded per b; {round,max} in [kc])

// ---------------- ETb[j][i] = bf16(exp(trans[i][j])), LDS-tiled transpose ----
__global__ __launch_bounds__(256)
void k_expT_bf16(const float* __restrict__ trans, __hip_bfloat16* __restrict__ ETb) {
    __shared__ float tile[32][33];
    int bi = blockIdx.x, bj = blockIdx.y;
    int tx = threadIdx.x & 31;
    int ty = threadIdx.x >> 5;
#pragma unroll
    for (int k = 0; k < 4; ++k) {
        int i = bi * 32 + ty + k * 8;
        tile[ty + k * 8][tx] = expf(trans[i * VV + bj * 32 + tx]);
    }
    __syncthreads();
#pragma unroll
    for (int k = 0; k < 4; ++k) {
        int j = bj * 32 + ty + k * 8;
        ETb[j * VV + bi * 32 + tx] = __float2bfloat16(tile[tx][ty + k * 8]);
    }
}

// ---------------- zero the flags ----------------
__global__ __launch_bounds__(256)
void k_zero(unsigned long long* __restrict__ flags) {
#pragma unroll
    for (int k = 0; k < 4; ++k)
        flags[threadIdx.x + k * 256] = 0ull;
}

// ---------------- feats GEMM: [T*B, H] x [V, H]^T + bias -> bf16 [B][T][V] ----
#define BM 64
#define BN 64
#define BK 32

__global__ __launch_bounds__(256)
void k_feats(const float* __restrict__ A, const float* __restrict__ W,
             const float* __restrict__ bias, __hip_bfloat16* __restrict__ feats) {
    __shared__ float As[BK][BM + 4];
    __shared__ float Bs[BK][BN + 4];
    int tid = threadIdx.x;
    int tx = tid & 15, ty = tid >> 4;
    int row0 = blockIdx.x * BM;
    int col0 = blockIdx.y * BN;
    float acc[4][4] = {};
    for (int kt = 0; kt < HH; kt += BK) {
#pragma unroll
        for (int s = 0; s < 2; ++s) {
            int slot = tid + s * 256;
            int row = slot >> 3;
            int f4 = slot & 7;
            float4 av = *(const float4*)&A[(size_t)(row0 + row) * HH + kt + f4 * 4];
            As[f4 * 4 + 0][row] = av.x; As[f4 * 4 + 1][row] = av.y;
            As[f4 * 4 + 2][row] = av.z; As[f4 * 4 + 3][row] = av.w;
            float4 bv = *(const float4*)&W[(size_t)(col0 + row) * HH + kt + f4 * 4];
            Bs[f4 * 4 + 0][row] = bv.x; Bs[f4 * 4 + 1][row] = bv.y;
            Bs[f4 * 4 + 2][row] = bv.z; Bs[f4 * 4 + 3][row] = bv.w;
        }
        __syncthreads();
#pragma unroll
        for (int k = 0; k < BK; ++k) {
            float4 a4 = *(const float4*)&As[k][ty * 4];
            float4 w4 = *(const float4*)&Bs[k][tx * 4];
            float av[4] = {a4.x, a4.y, a4.z, a4.w};
            float wv[4] = {w4.x, w4.y, w4.z, w4.w};
#pragma unroll
            for (int r = 0; r < 4; ++r)
#pragma unroll
                for (int c = 0; c < 4; ++c)
                    acc[r][c] = fmaf(av[r], wv[c], acc[r][c]);
        }
        __syncthreads();
    }
    float4 b4 = *(const float4*)&bias[col0 + tx * 4];
    float bv[4] = {b4.x, b4.y, b4.z, b4.w};
#pragma unroll
    for (int r = 0; r < 4; ++r) {
        int row = row0 + ty * 4 + r;   // row = t*BB + b
        int t = row >> 6;
        int bb = row & (BB - 1);
        __hip_bfloat16* dst = feats + ((size_t)bb * TT + t) * VV + col0 + tx * 4;
        __hip_bfloat162 p0, p1;
        p0.x = __float2bfloat16(acc[r][0] + bv[0]);
        p0.y = __float2bfloat16(acc[r][1] + bv[1]);
        p1.x = __float2bfloat16(acc[r][2] + bv[2]);
        p1.y = __float2bfloat16(acc[r][3] + bv[3]);
        *(__hip_bfloat162*)dst = p0;
        *(__hip_bfloat162*)(dst + 2) = p1;
    }
}

// ---------------- i-split scan: flag+payload exchange ----------------
__device__ __forceinline__ float bflo(unsigned int u) { return __uint_as_float(u << 16); }
__device__ __forceinline__ float bfhi(unsigned int u) { return __uint_as_float(u & 0xffff0000u); }

// dynamic LDS layout (bytes):
//   [0, 131072)          sET  ushort [512][128]
//   [131072, 139392)     sp   float [4][520]   (replicas, 8-bank shift)
//   [139392, 147584)     spart float [16][128]
#define SMEM_BYTES 147584

__global__ __launch_bounds__(256, 1)
void k_scan(const unsigned short* __restrict__ ETb,
            const __hip_bfloat16* __restrict__ feats,
            const int* __restrict__ lengths,
            float* __restrict__ zbuf, unsigned long long* __restrict__ flags,
            float* __restrict__ out) {
    extern __shared__ unsigned char smem[];
    unsigned short* sET = (unsigned short*)smem;
    float* sp    = (float*)(smem + 131072);
    float* spart = (float*)(smem + 139392);
    __shared__ float sred[8];

    int tid = threadIdx.x;
    int b   = blockIdx.x & 63;        // peers {b, b+64, b+128, b+192} -> same XCD (%8)
    int kc  = blockIdx.x >> 6;        // i-chunk 0..3
    int lane = tid & 63, wid = tid >> 6;
    int len = lengths[b];
    unsigned long long* flg = flags + b * 16;   // 128 B per b

    // ---- preload ET slice: columns [kc*128, +128) of all 512 rows ----
    {
        const uint4* Eg = (const uint4*)ETb;    // row = 64 uint4
        uint4* El = (uint4*)sET;                // row = 16 uint4
#pragma unroll
        for (int it = 0; it < 32; ++it) {
            int idx = tid + it * 256;           // 0..8191
            int j = idx >> 4, q = idx & 15;
            El[idx] = Eg[j * 64 + kc * 16 + q];
        }
    }

    float* z0 = zbuf;
    float* z1 = zbuf + BB * VV;

    // ---- init z buf0 slice + publish round 1 ----
    if (tid < CI) {
        int ig = kc * CI + tid;
        __hip_atomic_store(&z0[b * VV + ig], (ig == BOSI) ? 0.f : NEGV,
                           __ATOMIC_RELAXED, __HIP_MEMORY_SCOPE_AGENT);
    }
    __syncthreads();
    if (tid == 0) {
        float im = (kc == 0) ? 0.f : NEGV;     // chunk 0 holds BOS
        unsigned long long v = (1ull << 32) | (unsigned long long)__float_as_uint(im);
        __hip_atomic_store(&flg[kc], v, __ATOMIC_RELEASE, __HIP_MEMORY_SCOPE_AGENT);
    }

    int js  = tid >> 4;               // j-slice 0..15 (32 j each)
    int il8 = (tid & 15) * 8;         // 8 i's per thread
    int rep = js & 3;                 // p replica (bank-shifted)
    const __hip_bfloat16* fb = feats + (size_t)b * TT * VV;

    for (int t = 0; t < len; ++t) {
        const float* zr = (t & 1) ? z1 : z0;
        float*       zw = (t & 1) ? z0 : z1;

        // feats prefetch (independent of exchange -> overlaps poll)
        float ft = 0.f;
        if (tid < CI) ft = __bfloat162float(fb[(size_t)t * VV + kc * CI + tid]);

        // poll the 4 peer flags in parallel (lanes 0..3), payload = chunk max
        if (tid < NK) {
            unsigned tgt = (unsigned)(t + 1);
            unsigned long long v;
            do {
                v = __hip_atomic_load(&flg[tid], __ATOMIC_ACQUIRE, __HIP_MEMORY_SCOPE_AGENT);
            } while ((unsigned)(v >> 32) < tgt);
            sred[tid] = __uint_as_float((unsigned)v);
        }
        __syncthreads();
        float m = fmaxf(fmaxf(sred[0], sred[1]), fmaxf(sred[2], sred[3]));

        // coherent read of full score vector, p = exp(z - m) into 4 replicas
        unsigned long long vz = __hip_atomic_load(
            (const unsigned long long*)(zr + b * VV) + tid,
            __ATOMIC_RELAXED, __HIP_MEMORY_SCOPE_AGENT);
        float p0 = expf(__uint_as_float((unsigned int)vz) - m);
        float p1 = expf(__uint_as_float((unsigned int)(vz >> 32)) - m);
#pragma unroll
        for (int r = 0; r < 4; ++r)
            *(float2*)&sp[r * 520 + 2 * tid] = make_float2(p0, p1);
        __syncthreads();

        // matvec over LDS ET slice: a[i] = sum_j ET[j][i] * p[j]
        float a0 = 0.f, a1 = 0.f, a2 = 0.f, a3 = 0.f;
        float a4 = 0.f, a5 = 0.f, a6 = 0.f, a7 = 0.f;
#pragma unroll
        for (int j4 = 0; j4 < 8; ++j4) {
            int j = js * 32 + j4 * 4;
            float4 pv = *(const float4*)&sp[rep * 520 + j];
            float pj[4] = {pv.x, pv.y, pv.z, pv.w};
#pragma unroll
            for (int jj = 0; jj < 4; ++jj) {
                uint4 e = *(const uint4*)&sET[(j + jj) * CI + il8];
                float pq = pj[jj];
                a0 = fmaf(bflo(e.x), pq, a0); a1 = fmaf(bfhi(e.x), pq, a1);
                a2 = fmaf(bflo(e.y), pq, a2); a3 = fmaf(bfhi(e.y), pq, a3);
                a4 = fmaf(bflo(e.z), pq, a4); a5 = fmaf(bfhi(e.z), pq, a5);
                a6 = fmaf(bflo(e.w), pq, a6); a7 = fmaf(bfhi(e.w), pq, a7);
            }
        }
        *(float4*)&spart[js * CI + il8]     = make_float4(a0, a1, a2, a3);
        *(float4*)&spart[js * CI + il8 + 4] = make_float4(a4, a5, a6, a7);
        __syncthreads();

        // reduce 16 partials, z_new slice, chunk max, publish flag
        float zn = -INFINITY;
        if (wid < 2) {                      // tid < 128 == CI
            float s = 0.f;
#pragma unroll
            for (int q = 0; q < 16; ++q) s += spart[q * CI + tid];
            zn = m + logf(s) + ft;          // logf(0) = -inf for dead states: OK
            __hip_atomic_store(&zw[b * VV + kc * CI + tid], zn,
                               __ATOMIC_RELAXED, __HIP_MEMORY_SCOPE_AGENT);
            float cm = zn;
#pragma unroll
            for (int off = 32; off > 0; off >>= 1)
                cm = fmaxf(cm, __shfl_xor(cm, off, 64));
            if (lane == 0) sred[4 + wid] = cm;
        }
        __syncthreads();                    // drains z stores (vmcnt) + sred visible
        if (tid == 0) {
            float cmax = fmaxf(sred[4], sred[5]);
            unsigned long long v = ((unsigned long long)(unsigned)(t + 2) << 32) |
                                   (unsigned long long)__float_as_uint(cmax);
            __hip_atomic_store(&flg[kc], v, __ATOMIC_RELEASE, __HIP_MEMORY_SCOPE_AGENT);
        }
    }

    // ---- final LSE over all 512 states (chunk-0 block only) ----
    if (kc == 0) {
        if (tid < NK) {
            unsigned tgt = (unsigned)(len + 1);
            unsigned long long v;
            do {
                v = __hip_atomic_load(&flg[tid], __ATOMIC_ACQUIRE, __HIP_MEMORY_SCOPE_AGENT);
            } while ((unsigned)(v >> 32) < tgt);
            sred[tid] = __uint_as_float((unsigned)v);
        }
        __syncthreads();
        float m = fmaxf(fmaxf(sred[0], sred[1]), fmaxf(sred[2], sred[3]));
        const float* zf = (len & 1) ? z1 : z0;
        unsigned long long vz = __hip_atomic_load(
            (const unsigned long long*)(zf + b * VV) + tid,
            __ATOMIC_RELAXED, __HIP_MEMORY_SCOPE_AGENT);
        float s = expf(__uint_as_float((unsigned int)vz) - m) +
                  expf(__uint_as_float((unsigned int)(vz >> 32)) - m);
#pragma unroll
        for (int off = 32; off > 0; off >>= 1)
            s += __shfl_xor(s, off, 64);
        if (lane == 0) sred[4 + wid] = s;
        __syncthreads();
        if (tid == 0)
            out[b] = m + logf(sred[4] + sred[5] + sred[6] + sred[7]);
    }
}

extern "C" void kernel_launch(void* const* d_in, const int* in_sizes, int n_in,
                              void* d_out, int out_size, void* d_ws, size_t ws_size,
                              hipStream_t stream) {
    const float* enc     = (const float*)d_in[0];  // [T,B,H]
    const int*   lengths = (const int*)d_in[1];    // [B]
    const float* W       = (const float*)d_in[2];  // [V,H]
    const float* bias    = (const float*)d_in[3];  // [V]
    const float* trans   = (const float*)d_in[4];  // [V,V]
    float* out = (float*)d_out;

    char* ws = (char*)d_ws;
    __hip_bfloat16* ETb       = (__hip_bfloat16*)ws;
    __hip_bfloat16* feats     = (__hip_bfloat16*)(ws + (1 << 20));
    float*          zbuf      = (float*)(ws + (17 << 20));
    unsigned long long* flags = (unsigned long long*)(ws + (17 << 20) + (256 << 10));

    hipFuncSetAttribute((const void*)k_scan,
                        hipFuncAttributeMaxDynamicSharedMemorySize, SMEM_BYTES);

    hipLaunchKernelGGL(k_zero, dim3(1), dim3(256), 0, stream, flags);
    hipLaunchKernelGGL(k_expT_bf16, dim3(16, 16), dim3(256), 0, stream, trans, ETb);
    hipLaunchKernelGGL(k_feats, dim3((TT * BB) / BM, VV / BN), dim3(256), 0, stream,
                       enc, W, bias, feats);
    hipLaunchKernelGGL(k_scan, dim3(NK * BB), dim3(256), SMEM_BYTES, stream,
                       (const unsigned short*)ETb, feats, lengths, zbuf, flags, out);
}

// Round 6
// 877.009 us; speedup vs baseline: 4.6002x; 1.5756x over previous
//
#include <hip/hip_runtime.h>
#include <hip/hip_bf16.h>
#include <hip/hip_fp16.h>
#include <math.h>

#define TT 256
#define BB 64
#define HH 1024
#define VV 512
#define NEGV -10000.0f
#define BOSI 1
#define CI 128          // i-chunk per block
#define NK 4            // chunks (blocks) per batch element
#define NW 44           // payload words per chunk (43 data + 1 cm)
#define PSTRIDE 64      // u64 stride per chunk slot (512 B, padded)

// ws layout:
//   [0, 1M)       : ET float32 [VV][VV]   (ET[j][i] = exp(trans[i][j]))
//   [1M, 17M)     : feats bf16 [BB][TT][VV]
//   [17M, 17M+256K): payload u64 [BB][2 slots][NK][PSTRIDE]
//     word w<43: [63:48]=tag, [47:0]=3 f16 p-values p[3w..3w+2]
//     word 43  : [63:48]=tag, [31:0]=cm fp32

// ---------------- ET[j][i] = exp(trans[i][j]) fp32, LDS-tiled transpose ----
__global__ __launch_bounds__(256)
void k_expT(const float* __restrict__ trans, float* __restrict__ ET) {
    __shared__ float tile[32][33];
    int bi = blockIdx.x, bj = blockIdx.y;
    int tx = threadIdx.x & 31;
    int ty = threadIdx.x >> 5;
#pragma unroll
    for (int k = 0; k < 4; ++k) {
        int i = bi * 32 + ty + k * 8;
        tile[ty + k * 8][tx] = expf(trans[i * VV + bj * 32 + tx]);
    }
    __syncthreads();
#pragma unroll
    for (int k = 0; k < 4; ++k) {
        int j = bj * 32 + ty + k * 8;
        ET[j * VV + bi * 32 + tx] = tile[tx][ty + k * 8];
    }
}

// ---------------- zero payload (tags must start < 1; ws is poisoned 0xAA) ----
__global__ __launch_bounds__(256)
void k_zero(unsigned long long* __restrict__ pay) {
    pay[blockIdx.x * 256 + threadIdx.x] = 0ull;   // grid 128 -> 32768 words
}

// ---------------- feats GEMM: [T*B, H] x [V, H]^T + bias -> bf16 [B][T][V] ----
#define BM 64
#define BN 64
#define BK 32

__global__ __launch_bounds__(256)
void k_feats(const float* __restrict__ A, const float* __restrict__ W,
             const float* __restrict__ bias, __hip_bfloat16* __restrict__ feats) {
    __shared__ float As[BK][BM + 4];
    __shared__ float Bs[BK][BN + 4];
    int tid = threadIdx.x;
    int tx = tid & 15, ty = tid >> 4;
    int row0 = blockIdx.x * BM;
    int col0 = blockIdx.y * BN;
    float acc[4][4] = {};
    for (int kt = 0; kt < HH; kt += BK) {
#pragma unroll
        for (int s = 0; s < 2; ++s) {
            int slot = tid + s * 256;
            int row = slot >> 3;
            int f4 = slot & 7;
            float4 av = *(const float4*)&A[(size_t)(row0 + row) * HH + kt + f4 * 4];
            As[f4 * 4 + 0][row] = av.x; As[f4 * 4 + 1][row] = av.y;
            As[f4 * 4 + 2][row] = av.z; As[f4 * 4 + 3][row] = av.w;
            float4 bv = *(const float4*)&W[(size_t)(col0 + row) * HH + kt + f4 * 4];
            Bs[f4 * 4 + 0][row] = bv.x; Bs[f4 * 4 + 1][row] = bv.y;
            Bs[f4 * 4 + 2][row] = bv.z; Bs[f4 * 4 + 3][row] = bv.w;
        }
        __syncthreads();
#pragma unroll
        for (int k = 0; k < BK; ++k) {
            float4 a4 = *(const float4*)&As[k][ty * 4];
            float4 w4 = *(const float4*)&Bs[k][tx * 4];
            float av[4] = {a4.x, a4.y, a4.z, a4.w};
            float wv[4] = {w4.x, w4.y, w4.z, w4.w};
#pragma unroll
            for (int r = 0; r < 4; ++r)
#pragma unroll
                for (int c = 0; c < 4; ++c)
                    acc[r][c] = fmaf(av[r], wv[c], acc[r][c]);
        }
        __syncthreads();
    }
    float4 b4 = *(const float4*)&bias[col0 + tx * 4];
    float bv[4] = {b4.x, b4.y, b4.z, b4.w};
#pragma unroll
    for (int r = 0; r < 4; ++r) {
        int row = row0 + ty * 4 + r;   // row = t*BB + b
        int t = row >> 6;
        int bb = row & (BB - 1);
        __hip_bfloat16* dst = feats + ((size_t)bb * TT + t) * VV + col0 + tx * 4;
        __hip_bfloat162 p0, p1;
        p0.x = __float2bfloat16(acc[r][0] + bv[0]);
        p0.y = __float2bfloat16(acc[r][1] + bv[1]);
        p1.x = __float2bfloat16(acc[r][2] + bv[2]);
        p1.y = __float2bfloat16(acc[r][3] + bv[3]);
        *(__hip_bfloat162*)dst = p0;
        *(__hip_bfloat162*)(dst + 2) = p1;
    }
}

// ---------------- i-split scan: register-resident ET, payload exchange -------
__global__ __launch_bounds__(256, 1)
void k_scan(const float* __restrict__ ETg,
            const __hip_bfloat16* __restrict__ feats,
            const int* __restrict__ lengths,
            unsigned long long* __restrict__ pay,
            float* __restrict__ out) {
    __shared__ float spf[16 * 36];   // p fp32, row js (32 j), pad to 36 (bank shift)
    __shared__ float spart[16 * CI]; // 16 js-partials x 128 i
    __shared__ float sLz[CI];
    __shared__ float sm[NK];
    __shared__ float sred[2];
    __shared__ float sfin[4];

    int tid = threadIdx.x;
    int b   = blockIdx.x & 63;       // peers {b, b+64, b+128, b+192} same XCD (%8)
    int kc  = blockIdx.x >> 6;       // i-chunk 0..3
    int lane = tid & 63, wid = tid >> 6;
    int len = lengths[b];
    int js = tid >> 4;               // j-slice 0..15 (32 j each)
    int ig = tid & 15;
    int i0 = ig * 8;                 // 8 i's per thread (within chunk)

    // payload slot base: pay[((b*2 + s)*NK + c)*PSTRIDE + w]
#define PSLOT(s, c) (pay + ((size_t)(b * 2 + (s)) * NK + (c)) * PSTRIDE)

    // ---- one-time: ET sub-block into 256 VGPRs ----
    // rows j = js*32 .. +32, cols i = kc*128 + i0 .. +8
    float eta[256];
    {
        const float* base = ETg + (size_t)(js * 32) * VV + kc * CI + i0;
#pragma unroll
        for (int jj = 0; jj < 32; ++jj) {
            float4 v0 = *(const float4*)(base + jj * VV);
            float4 v1 = *(const float4*)(base + jj * VV + 4);
            eta[jj * 8 + 0] = v0.x; eta[jj * 8 + 1] = v0.y;
            eta[jj * 8 + 2] = v0.z; eta[jj * 8 + 3] = v0.w;
            eta[jj * 8 + 4] = v1.x; eta[jj * 8 + 5] = v1.y;
            eta[jj * 8 + 6] = v1.z; eta[jj * 8 + 7] = v1.w;
        }
    }

    // ---- init publish: round 1 -> slot 1 (p = exp(z0 - cm0)) ----
    if (tid < NW) {
        float cm0 = (kc == 0) ? 0.f : NEGV;
        unsigned long long v;
        if (tid == NW - 1) {
            v = (1ull << 48) | (unsigned long long)__float_as_uint(cm0);
        } else {
            unsigned long long h[3] = {0ull, 0ull, 0ull};
#pragma unroll
            for (int r = 0; r < 3; ++r) {
                int idx = 3 * tid + r;
                if (idx < CI) {
                    int gi = kc * CI + idx;
                    float z = (gi == BOSI) ? 0.f : NEGV;
                    h[r] = (unsigned long long)__half_as_ushort(__float2half(expf(z - cm0)));
                }
            }
            v = (1ull << 48) | (h[2] << 32) | (h[1] << 16) | h[0];
        }
        __hip_atomic_store(&PSLOT(1, kc)[tid], v, __ATOMIC_RELAXED, __HIP_MEMORY_SCOPE_AGENT);
    }

    const __hip_bfloat16* fb = feats + (size_t)b * TT * VV;
    int pc = (tid >= 132) ? 3 : (tid >= 88) ? 2 : (tid >= 44) ? 1 : 0;
    int pw = tid - pc * 44;          // word index within chunk (valid for tid<176)

    for (int t = 0; t < len; ++t) {
        // feats prefetch (independent of exchange -> overlaps poll)
        float ft = 0.f;
        if (tid < CI) ft = __bfloat162float(fb[(size_t)t * VV + kc * CI + tid]);

        // ---- poll all 4 chunks' payloads (tid<176), unpack into LDS ----
        if (tid < NK * NW) {
            const unsigned long long* wp = &PSLOT((t + 1) & 1, pc)[pw];
            unsigned tgt = (unsigned)(t + 1);
            unsigned long long v;
            do {
                v = __hip_atomic_load(wp, __ATOMIC_RELAXED, __HIP_MEMORY_SCOPE_AGENT);
            } while ((unsigned)(v >> 48) < tgt);
            if (pw == NW - 1) {
                sm[pc] = __uint_as_float((unsigned)v);
            } else {
#pragma unroll
                for (int r = 0; r < 3; ++r) {
                    int idx = 3 * pw + r;
                    if (idx < CI) {
                        int j = pc * CI + idx;
                        spf[36 * (j >> 5) + (j & 31)] =
                            __half2float(__ushort_as_half((unsigned short)(v >> (16 * r))));
                    }
                }
            }
        }
        __syncthreads();   // B1: spf + sm ready

        float M = fmaxf(fmaxf(sm[0], sm[1]), fmaxf(sm[2], sm[3]));
        float wloc = expf(sm[js >> 2] - M);   // weight of my js's chunk

        // ---- matvec from registers: a[i] = sum_{j in my slice} eta * p ----
        float a0 = 0.f, a1 = 0.f, a2 = 0.f, a3 = 0.f;
        float a4 = 0.f, a5 = 0.f, a6 = 0.f, a7 = 0.f;
#pragma unroll
        for (int j4 = 0; j4 < 8; ++j4) {
            float4 pv = *(const float4*)&spf[js * 36 + j4 * 4];   // broadcast
            float pj[4] = {pv.x, pv.y, pv.z, pv.w};
#pragma unroll
            for (int u = 0; u < 4; ++u) {
                int jj = j4 * 4 + u;
                float pq = pj[u];
                a0 = fmaf(eta[jj * 8 + 0], pq, a0);
                a1 = fmaf(eta[jj * 8 + 1], pq, a1);
                a2 = fmaf(eta[jj * 8 + 2], pq, a2);
                a3 = fmaf(eta[jj * 8 + 3], pq, a3);
                a4 = fmaf(eta[jj * 8 + 4], pq, a4);
                a5 = fmaf(eta[jj * 8 + 5], pq, a5);
                a6 = fmaf(eta[jj * 8 + 6], pq, a6);
                a7 = fmaf(eta[jj * 8 + 7], pq, a7);
            }
        }
        *(float4*)&spart[js * CI + i0]     = make_float4(a0 * wloc, a1 * wloc, a2 * wloc, a3 * wloc);
        *(float4*)&spart[js * CI + i0 + 4] = make_float4(a4 * wloc, a5 * wloc, a6 * wloc, a7 * wloc);
        __syncthreads();   // B2: spart ready

        // ---- reduce 16 partials, z_new, chunk max ----
        if (tid < CI) {
            float s = 0.f;
#pragma unroll
            for (int q = 0; q < 16; ++q) s += spart[q * CI + tid];
            float zn = M + logf(s) + ft;     // logf(0) = -inf for dead states: OK
            sLz[tid] = zn;
            float cmv = zn;
#pragma unroll
            for (int off = 32; off > 0; off >>= 1)
                cmv = fmaxf(cmv, __shfl_xor(cmv, off, 64));
            if (lane == 0) sred[wid] = cmv;
        }
        __syncthreads();   // B3: sLz + sred ready

        // ---- pack + publish round t+2 -> slot t&1 ----
        if (tid < NW) {
            float cm = fmaxf(sred[0], sred[1]);
            unsigned long long tg = (unsigned long long)(unsigned)(t + 2) << 48;
            unsigned long long v;
            if (tid == NW - 1) {
                v = tg | (unsigned long long)__float_as_uint(cm);
            } else {
                unsigned long long h[3] = {0ull, 0ull, 0ull};
#pragma unroll
                for (int r = 0; r < 3; ++r) {
                    int idx = 3 * tid + r;
                    if (idx < CI)
                        h[r] = (unsigned long long)__half_as_ushort(
                                   __float2half(expf(sLz[idx] - cm)));
                }
                v = tg | (h[2] << 32) | (h[1] << 16) | h[0];
            }
            __hip_atomic_store(&PSLOT(t & 1, kc)[tid], v, __ATOMIC_RELAXED, __HIP_MEMORY_SCOPE_AGENT);
        }
        // no barrier needed: next poll self-validates via tags; LDS reuse ordered by B1/B2/B3
    }

    // ---- final LSE over all 512 states (chunk-0 block only) ----
    if (kc == 0) {
        if (tid < NK * NW) {
            const unsigned long long* wp = &PSLOT((len + 1) & 1, pc)[pw];
            unsigned tgt = (unsigned)(len + 1);
            unsigned long long v;
            do {
                v = __hip_atomic_load(wp, __ATOMIC_RELAXED, __HIP_MEMORY_SCOPE_AGENT);
            } while ((unsigned)(v >> 48) < tgt);
            if (pw == NW - 1) {
                sm[pc] = __uint_as_float((unsigned)v);
            } else {
#pragma unroll
                for (int r = 0; r < 3; ++r) {
                    int idx = 3 * pw + r;
                    if (idx < CI) {
                        int j = pc * CI + idx;
                        spf[36 * (j >> 5) + (j & 31)] =
                            __half2float(__ushort_as_half((unsigned short)(v >> (16 * r))));
                    }
                }
            }
        }
        __syncthreads();
        float M = fmaxf(fmaxf(sm[0], sm[1]), fmaxf(sm[2], sm[3]));
        int j0 = 2 * tid;                       // j0, j0+1 in same chunk (j0 even)
        float w0 = expf(sm[j0 >> 7] - M);
        float v0 = spf[36 * (j0 >> 5) + (j0 & 31)];
        float v1 = spf[36 * ((j0 + 1) >> 5) + ((j0 + 1) & 31)];
        float s = (v0 + v1) * w0;
#pragma unroll
        for (int off = 32; off > 0; off >>= 1)
            s += __shfl_xor(s, off, 64);
        if (lane == 0) sfin[wid] = s;
        __syncthreads();
        if (tid == 0)
            out[b] = M + logf(sfin[0] + sfin[1] + sfin[2] + sfin[3]);
    }
#undef PSLOT
}

extern "C" void kernel_launch(void* const* d_in, const int* in_sizes, int n_in,
                              void* d_out, int out_size, void* d_ws, size_t ws_size,
                              hipStream_t stream) {
    const float* enc     = (const float*)d_in[0];  // [T,B,H]
    const int*   lengths = (const int*)d_in[1];    // [B]
    const float* W       = (const float*)d_in[2];  // [V,H]
    const float* bias    = (const float*)d_in[3];  // [V]
    const float* trans   = (const float*)d_in[4];  // [V,V]
    float* out = (float*)d_out;

    char* ws = (char*)d_ws;
    float*          ETg   = (float*)ws;
    __hip_bfloat16* feats = (__hip_bfloat16*)(ws + (1 << 20));
    unsigned long long* pay = (unsigned long long*)(ws + (17 << 20));

    hipLaunchKernelGGL(k_zero, dim3(128), dim3(256), 0, stream, pay);
    hipLaunchKernelGGL(k_expT, dim3(16, 16), dim3(256), 0, stream, trans, ETg);
    hipLaunchKernelGGL(k_feats, dim3((TT * BB) / BM, VV / BN), dim3(256), 0, stream,
                       enc, W, bias, feats);
    hipLaunchKernelGGL(k_scan, dim3(NK * BB), dim3(256), 0, stream,
                       ETg, feats, lengths, pay, out);
}